// Round 15
// baseline (2234.538 us; speedup 1.0000x reference)
//
#include <hip/hip_runtime.h>

#define NN 200000
#define NE 400000
#define NFEAT 78
#define DIM 128
#define NLAYERS 5
#define NGRAPHS 8192
#define BN_EPS_C 1e-5f
#define NSLOT 32

typedef __attribute__((ext_vector_type(8))) short short8;
typedef __attribute__((ext_vector_type(8))) unsigned short ushort8;
typedef __attribute__((ext_vector_type(4))) float f32x4;

__device__ inline float bf2f(unsigned short u) {
    union { unsigned int i; float f; } c; c.i = ((unsigned int)u) << 16; return c.f;
}
__device__ inline unsigned short f2bf(float f) {
    union { float f; unsigned int i; } c; c.f = f;
    unsigned int x = c.i;
    x += 0x7FFFu + ((x >> 16) & 1u);      // RNE
    return (unsigned short)(x >> 16);
}

// ---------------- fused GIN MLP: Z = maybe_relu(relu(A@W1+b1)@W2+b2) ----------------
// HALF-PASS restructure of the r14 best: the occupancy limiter was the 128 f32
// accumulators (AGPR) per wave (64 VGPR + 128 AGPR ~= 192 -> 2 waves/SIMD, 30% occ).
// Two 16-row half-passes (#pragma unroll 1) keep only acc[8]+acc2[8] (64) live ->
// ~128 total regs -> 4 waves/SIMD target. C1 through a PER-WAVE 4KB LDS region
// (16 KB/block). Global access pattern, block shape (256thr/128rows/1563blocks),
// and scalar Z stores are byte-identical to the measured-best r14 dataflow
// (LDS-bounce stores: 2-3x HBM write amplification r9/r10; setprio: spill trigger r13).
// Zero barriers (C1 regions are wave-private).
template<int RELU2, int STATS>
__global__ __launch_bounds__(256, 4) void gin_mlp_kernel(
    const unsigned short* __restrict__ A,
    const unsigned short* __restrict__ W1d, const unsigned short* __restrict__ W2d,
    const float* __restrict__ b1, const float* __restrict__ b2,
    unsigned short* __restrict__ Z, float* __restrict__ stats_base)
{
    __shared__ unsigned short C1[4][2048];        // 4 waves x 4 KB = 16 KB

    int t = threadIdx.x;
    int r0 = blockIdx.x * 128;
    int lane = t & 63;
    int wv = t >> 6;          // wave 0..3
    int l15 = lane & 15;
    int lg = lane >> 4;       // 0..3
    char* Wlds = (char*)C1[wv];

    float b1v[8], b2v[8];
#pragma unroll
    for (int nt = 0; nt < 8; ++nt) { b1v[nt] = b1[nt * 16 + l15]; b2v[nt] = b2[nt * 16 + l15]; }

    f32x4 zero4 = {0.f, 0.f, 0.f, 0.f};

#pragma unroll 1
    for (int mt = 0; mt < 2; ++mt) {
        // A-fragment source row for this half (clamped; OOB rows never stored)
        int ra = r0 + wv * 32 + mt * 16 + l15;
        if (ra > NN - 1) ra = NN - 1;
        const unsigned short* __restrict__ Arow = A + (size_t)ra * DIM;

        f32x4 acc[8];
#pragma unroll
        for (int nt = 0; nt < 8; ++nt) acc[nt] = zero4;

        // GEMM1 half (interleaved loads; compiler schedules)
#pragma unroll
        for (int ks = 0; ks < 4; ++ks) {
            int kgp = ks * 4 + lg;
            short8 a = *(const short8*)(Arow + kgp * 8);
#pragma unroll
            for (int nt = 0; nt < 8; ++nt) {
                short8 b = *(const short8*)(W1d + (size_t)(kgp * 128 + nt * 16 + l15) * 8);
                acc[nt] = __builtin_amdgcn_mfma_f32_16x16x32_bf16(a, b, acc[nt], 0, 0, 0);
            }
        }

        // C1 half -> wave-private LDS (row-major + byte-XOR (lr&7)<<4), relu+bias
#pragma unroll
        for (int nt = 0; nt < 8; ++nt)
#pragma unroll
            for (int rg = 0; rg < 4; ++rg) {
                int lr = lg * 4 + rg;             // 0..15
                int c = nt * 16 + l15;
                float v = fmaxf(acc[nt][rg] + b1v[nt], 0.f);
                unsigned byte = (unsigned)(lr * 256 + c * 2) ^ (unsigned)((lr & 7) << 4);
                *(unsigned short*)(Wlds + byte) = f2bf(v);
            }

        f32x4 acc2[8];
#pragma unroll
        for (int nt = 0; nt < 8; ++nt) acc2[nt] = zero4;

        // GEMM2 half: A-frags from wave LDS (XOR reads, own rows), W2 from global/L2
#pragma unroll
        for (int ks = 0; ks < 4; ++ks) {
            int kgp = ks * 4 + lg;
            unsigned ba = (unsigned)(l15 * 256 + kgp * 16) ^ (unsigned)((l15 & 7) << 4);
            short8 a2 = *(const short8*)(Wlds + ba);
#pragma unroll
            for (int nt = 0; nt < 8; ++nt) {
                short8 b = *(const short8*)(W2d + (size_t)(kgp * 128 + nt * 16 + l15) * 8);
                acc2[nt] = __builtin_amdgcn_mfma_f32_16x16x32_bf16(a2, b, acc2[nt], 0, 0, 0);
            }
        }

        // epilogue half: scalar Z stores + stats shfl-reduce + replicated atomics
#pragma unroll
        for (int nt = 0; nt < 8; ++nt) {
            float sum8 = 0.f, sq8 = 0.f;
            int c = nt * 16 + l15;
#pragma unroll
            for (int rg = 0; rg < 4; ++rg) {
                int rr = wv * 32 + mt * 16 + lg * 4 + rg;
                int r = r0 + rr;
                if (r < NN) {
                    float v = acc2[nt][rg] + b2v[nt];
                    if (RELU2) v = fmaxf(v, 0.f);
                    Z[(size_t)r * DIM + c] = f2bf(v);
                    if (STATS) { sum8 += v; sq8 += v * v; }
                }
            }
            if (STATS) {
                sum8 += __shfl_xor(sum8, 16); sum8 += __shfl_xor(sum8, 32);
                sq8  += __shfl_xor(sq8, 16);  sq8  += __shfl_xor(sq8, 32);
                if (lg == 0) {
                    float* sb = stats_base + (size_t)(blockIdx.x & (NSLOT - 1)) * 256;
                    atomicAdd(&sb[c], sum8);
                    atomicAdd(&sb[128 + c], sq8);
                }
            }
        }
    }
}

// ---------------- weight conversion: fp32 [K][128] -> fragment-direct bf16 ----------------
__global__ __launch_bounds__(256) void wconv_kernel(
    const float* __restrict__ ini_w1, const float* __restrict__ ini_w2,
    const float* __restrict__ gw1, const float* __restrict__ gw2,
    unsigned short* __restrict__ Wd)
{
    int id = blockIdx.x * 256 + threadIdx.x;     // 0..16383
    int k = id >> 7, n = id & 127;
    int y = blockIdx.y;
    float v;
    if (y == 0)      v = (k < NFEAT) ? ini_w1[k * DIM + n] : 0.f;
    else if (y == 1) v = ini_w2[k * DIM + n];
    else if (y < 7)  v = gw1[(size_t)(y - 2) * DIM * DIM + k * DIM + n];
    else             v = gw2[(size_t)(y - 7) * DIM * DIM + k * DIM + n];
    int kg = k >> 3;
    Wd[(size_t)y * 16384 + (size_t)(kg * 128 + n) * 8 + (k & 7)] = f2bf(v);
}

// ---------------- x padding: fp32 [NN][78] -> bf16 [NN][128] (zero-pad) ----------------
__global__ __launch_bounds__(256) void xpad_kernel(
    const float* __restrict__ x, unsigned short* __restrict__ xp)
{
    int t = blockIdx.x * 256 + threadIdx.x;      // NN*16 exactly
    int n = t >> 4, j = t & 15;
    ushort8 o;
#pragma unroll
    for (int i = 0; i < 8; ++i) {
        int c = j * 8 + i;
        o[i] = (c < NFEAT) ? f2bf(x[(size_t)n * NFEAT + c]) : (unsigned short)0;
    }
    *(ushort8*)(xp + (size_t)n * DIM + j * 8) = o;
}

// ---------------- CSR build (once per launch) ----------------
__global__ __launch_bounds__(256) void deg_kernel(const int* __restrict__ ei, int* __restrict__ deg)
{
    int e = blockIdx.x * 256 + threadIdx.x;
    if (e >= NE) return;
    atomicAdd(&deg[ei[NE + e]], 1);
}

__global__ __launch_bounds__(256) void scanA_kernel(
    const int* __restrict__ deg, int* __restrict__ cursor, int* __restrict__ partials)
{
    __shared__ int sh[256];
    int i = blockIdx.x * 256 + threadIdx.x;
    int v = (i < NN) ? deg[i] : 0;
    sh[threadIdx.x] = v;
    __syncthreads();
    for (int off = 1; off < 256; off <<= 1) {
        int t2 = (threadIdx.x >= off) ? sh[threadIdx.x - off] : 0;
        __syncthreads();
        sh[threadIdx.x] += t2;
        __syncthreads();
    }
    int incl = sh[threadIdx.x];
    if (i < NN) cursor[i] = incl - v;
    if (threadIdx.x == 255) partials[blockIdx.x] = incl;
}

__global__ __launch_bounds__(1024) void scanB_kernel(int* __restrict__ partials, int nb)
{
    __shared__ int sh[1024];
    int i = threadIdx.x;
    int v = (i < nb) ? partials[i] : 0;
    sh[i] = v;
    __syncthreads();
    for (int off = 1; off < 1024; off <<= 1) {
        int t2 = (i >= off) ? sh[i - off] : 0;
        __syncthreads();
        sh[i] += t2;
        __syncthreads();
    }
    if (i < nb) partials[i] = sh[i] - v;
}

__global__ __launch_bounds__(256) void scanC_kernel(
    int* __restrict__ cursor, const int* __restrict__ partials)
{
    int i = blockIdx.x * 256 + threadIdx.x;
    if (i < NN) cursor[i] += partials[blockIdx.x];
}

__global__ __launch_bounds__(256) void fill_kernel(
    const int* __restrict__ ei, int* __restrict__ cursor, int* __restrict__ csr_src)
{
    int e = blockIdx.x * 256 + threadIdx.x;
    if (e >= NE) return;
    int slot = atomicAdd(&cursor[ei[NE + e]], 1);
    csr_src[slot] = ei[e];
}

// graph_ptr[g] = first node index with batch >= g (batch sorted); gptr[NGRAPHS] = NN
__global__ __launch_bounds__(256) void gptr_kernel(
    const int* __restrict__ batch, int* __restrict__ gptr)
{
    int n = blockIdx.x * 256 + threadIdx.x;
    if (n > NN) return;
    int b1 = (n < NN) ? batch[n] : NGRAPHS;
    int b0 = (n == 0) ? -1 : batch[n - 1];
    for (int g = b0 + 1; g <= b1; ++g) gptr[g] = n;
}

__global__ void ident_kernel(float* __restrict__ aff)
{
    int d = threadIdx.x;
    aff[d] = 1.f;
    aff[DIM + d] = 0.f;
}

// ---------------- affine-fused gather ----------------
// agg[n] = a ⊙ (z[n] + sum_nbr z) + (deg+1)·c ; edge loop unrolled x2 (order-preserving)
__global__ __launch_bounds__(256) void gather_kernel(
    const unsigned short* __restrict__ z, const int* __restrict__ cursor,
    const int* __restrict__ csr_src, const float* __restrict__ aff,
    unsigned short* __restrict__ agg)
{
    int t = blockIdx.x * 256 + threadIdx.x;      // NN*16 exactly
    int n = t >> 4, j = t & 15;
    int end = cursor[n];
    int beg = (n == 0) ? 0 : cursor[n - 1];
    ushort8 sv = *(const ushort8*)(z + (size_t)n * DIM + j * 8);
    float a[8];
#pragma unroll
    for (int i = 0; i < 8; ++i) a[i] = bf2f(sv[i]);
    int e = beg;
    for (; e + 1 < end; e += 2) {
        int s0 = csr_src[e];
        int s1 = csr_src[e + 1];
        ushort8 v0 = *(const ushort8*)(z + (size_t)s0 * DIM + j * 8);
        ushort8 v1 = *(const ushort8*)(z + (size_t)s1 * DIM + j * 8);
#pragma unroll
        for (int i = 0; i < 8; ++i) a[i] += bf2f(v0[i]);
#pragma unroll
        for (int i = 0; i < 8; ++i) a[i] += bf2f(v1[i]);
    }
    if (e < end) {
        int s = csr_src[e];
        ushort8 v = *(const ushort8*)(z + (size_t)s * DIM + j * 8);
#pragma unroll
        for (int i = 0; i < 8; ++i) a[i] += bf2f(v[i]);
    }
    float cnt = (float)(end - beg + 1);
    ushort8 o;
#pragma unroll
    for (int i = 0; i < 8; ++i) {
        float av = aff[j * 8 + i];
        float cv = aff[DIM + j * 8 + i];
        o[i] = f2bf(fmaf(av, a[i], cnt * cv));
    }
    *(ushort8*)(agg + (size_t)n * DIM + j * 8) = o;
}

// ---------------- per-graph pool: out[g] += lcw*(a⊙segsum(z) + cnt*c) (+ cnt*lcb) ----------------
__global__ __launch_bounds__(128) void pool_kernel(
    const unsigned short* __restrict__ z, const int* __restrict__ gptr,
    const float* __restrict__ aff, const float* __restrict__ lcw, int l,
    const float* __restrict__ lcb_p, int add_lcb, float* __restrict__ out)
{
    int g = blockIdx.x;
    int d = threadIdx.x;
    int p0 = gptr[g], p1 = gptr[g + 1];
    float S = 0.f;
    for (int n = p0; n < p1; ++n) S += bf2f(z[(size_t)n * DIM + d]);
    float w = lcw[l];
    float cnt = (float)(p1 - p0);
    float v = w * fmaf(aff[d], S, cnt * aff[DIM + d]);
    if (add_lcb) v = fmaf(cnt, *lcb_p, v);
    out[(size_t)g * DIM + d] += v;
}

// per-layer: affine[d] = gamma*rsqrt(var+eps); affine[128+d] = beta - mean*a
__global__ void finalize_kernel(
    const float* __restrict__ slots, const float* __restrict__ gamma,
    const float* __restrict__ beta, float* __restrict__ aff)
{
    int d = threadIdx.x;
    float s = 0.f, sq = 0.f;
    for (int i = 0; i < NSLOT; ++i) {
        s  += slots[i * 256 + d];
        sq += slots[i * 256 + 128 + d];
    }
    float mean = s * (1.0f / NN);
    float var = sq * (1.0f / NN) - mean * mean;
    float a = gamma[d] * rsqrtf(var + BN_EPS_C);
    aff[d] = a;
    aff[DIM + d] = beta[d] - mean * a;
}

extern "C" void kernel_launch(void* const* d_in, const int* in_sizes, int n_in,
                              void* d_out, int out_size, void* d_ws, size_t ws_size,
                              hipStream_t stream)
{
    const float* x      = (const float*)d_in[0];
    const int*   ei     = (const int*)d_in[1];
    const int*   batch  = (const int*)d_in[2];
    const float* ini_w1 = (const float*)d_in[4];
    const float* ini_b1 = (const float*)d_in[5];
    const float* ini_w2 = (const float*)d_in[6];
    const float* ini_b2 = (const float*)d_in[7];
    const float* gw1    = (const float*)d_in[8];
    const float* gb1    = (const float*)d_in[9];
    const float* gw2    = (const float*)d_in[10];
    const float* gb2    = (const float*)d_in[11];
    const float* gamma  = (const float*)d_in[12];
    const float* beta   = (const float*)d_in[13];
    const float* lcw    = (const float*)d_in[14];
    const float* lcb    = (const float*)d_in[15];
    float* out = (float*)d_out;

    size_t NHs = (size_t)NN * DIM;                       // ushort count per node buffer
    unsigned short* bufA = (unsigned short*)d_ws;
    unsigned short* bufB = bufA + NHs;                   // also holds padded x pre-ini
    unsigned short* Wd   = bufB + NHs;                   // 12 * 16384 ushorts
    float* stats  = (float*)(Wd + 12 * 16384);           // NLAYERS * NSLOT * 256
    float* affine = stats + (size_t)NLAYERS * NSLOT * 256; // (NLAYERS+1) * 256
    int* deg      = (int*)(affine + (NLAYERS + 1) * 256);
    int* cursor   = deg + NN;
    int* csr_src  = cursor + NN;
    int* partials = csr_src + NE;
    int* gptr     = partials + 1024;
    size_t need = (size_t)((char*)(gptr + NGRAPHS + 1) - (char*)d_ws);

    hipMemsetAsync(out, 0, (size_t)NGRAPHS * DIM * sizeof(float), stream);
    if (ws_size < need) return;   // diagnostic: zero output signals ws shortfall

    hipMemsetAsync(stats, 0, (size_t)NLAYERS * NSLOT * 256 * sizeof(float), stream);
    hipMemsetAsync(deg, 0, NN * sizeof(int), stream);

    int nb = (NN + 255) / 256;     // 782
    int eb = (NE + 255) / 256;

    deg_kernel<<<eb, 256, 0, stream>>>(ei, deg);
    scanA_kernel<<<nb, 256, 0, stream>>>(deg, cursor, partials);
    scanB_kernel<<<1, 1024, 0, stream>>>(partials, nb);
    scanC_kernel<<<nb, 256, 0, stream>>>(cursor, partials);
    fill_kernel<<<eb, 256, 0, stream>>>(ei, cursor, csr_src);
    gptr_kernel<<<(NN + 256) / 256 + 1, 256, 0, stream>>>(batch, gptr);
    ident_kernel<<<1, 128, 0, stream>>>(affine);

    xpad_kernel<<<NN * 16 / 256, 256, 0, stream>>>(x, bufB);
    wconv_kernel<<<dim3(64, 12), 256, 0, stream>>>(ini_w1, ini_w2, gw1, gw2, Wd);

    int gin_blocks = (NN + 127) / 128;   // 1563

    // ini_embed: bufA = relu(xp@W1+b1)@W2+b2 (no relu, no stats)
    gin_mlp_kernel<0, 0><<<gin_blocks, 256, 0, stream>>>(
        bufB, Wd, Wd + 16384, ini_b1, ini_b2, bufA, nullptr);

    unsigned short* prev = bufA;
    for (int l = 0; l < NLAYERS; ++l) {
        unsigned short* nxt = (prev == bufA) ? bufB : bufA;
        // nxt = a_{l-1} ⊙ (z_prev + Σ z_prev[nbr]) + (deg+1)·c_{l-1}
        gather_kernel<<<NN * 16 / 256, 256, 0, stream>>>(
            prev, cursor, csr_src, affine + (size_t)l * 256, nxt);
        // nxt = relu(relu(nxt@W1+b1)@W2+b2), in-place; stats fused
        gin_mlp_kernel<1, 1><<<gin_blocks, 256, 0, stream>>>(
            nxt, Wd + (size_t)(2 + l) * 16384, Wd + (size_t)(7 + l) * 16384,
            gb1 + l * DIM, gb2 + l * DIM, nxt, stats + (size_t)l * NSLOT * 256);
        finalize_kernel<<<1, 128, 0, stream>>>(
            stats + (size_t)l * NSLOT * 256, gamma + l * DIM, beta + l * DIM,
            affine + (size_t)(l + 1) * 256);
        // out += lcw[l]*(a_l ⊙ segsum(z_l) + cnt*c_l) (+ cnt*lcb on l==0)
        pool_kernel<<<NGRAPHS, 128, 0, stream>>>(
            nxt, gptr, affine + (size_t)(l + 1) * 256, lcw, l, lcb,
            (l == 0) ? 1 : 0, out);
        prev = nxt;
    }
}

// Round 16
// 735.179 us; speedup vs baseline: 3.0394x; 3.0394x over previous
//
#include <hip/hip_runtime.h>

#define NN 200000
#define NE 400000
#define NFEAT 78
#define DIM 128
#define NLAYERS 5
#define NGRAPHS 8192
#define BN_EPS_C 1e-5f
#define NSLOT 32

typedef __attribute__((ext_vector_type(8))) short short8;
typedef __attribute__((ext_vector_type(8))) unsigned short ushort8;
typedef __attribute__((ext_vector_type(4))) float f32x4;

__device__ inline float bf2f(unsigned short u) {
    union { unsigned int i; float f; } c; c.i = ((unsigned int)u) << 16; return c.f;
}
__device__ inline unsigned short f2bf(float f) {
    union { float f; unsigned int i; } c; c.f = f;
    unsigned int x = c.i;
    x += 0x7FFFu + ((x >> 16) & 1u);      // RNE
    return (unsigned short)(x >> 16);
}

// ---------------- fused GIN MLP: Z = maybe_relu(relu(A@W1+b1)@W2+b2) ----------------
// r14 body EXACT (best measured: 694us total, gin 52.7us). Single change vs r14:
// __launch_bounds__(256, 2) — true per-wave footprint is ~64 VGPR + 128 AGPR = 192
// (occupancy bucket 8 waves/CU, measured 30%); min-waves=2 keeps that occupancy but
// raises the regalloc budget 128->256 so the compiler can batch more of the 40
// independent L2 operand loads per GEMM phase WITHOUT forcing (forcing attempts:
// r12 silently undone, r13 setprio-spill, r15 runtime-loop scratch catastrophe).
// HOIST=1 (layers): grouped operand loads. HOIST=0 (ini): interleaved (r12 anomaly).
// Scalar Z stores (LDS-bounce: 2-3x HBM write amplification, r9/r10). Zero barriers.
template<int RELU2, int STATS, int HOIST>
__global__ __launch_bounds__(256, 2) void gin_mlp_kernel(
    const unsigned short* __restrict__ A,
    const unsigned short* __restrict__ W1d, const unsigned short* __restrict__ W2d,
    const float* __restrict__ b1, const float* __restrict__ b2,
    unsigned short* __restrict__ Z, float* __restrict__ stats_base)
{
    __shared__ unsigned short C1[128 * 128];        // 32 KB

    int t = threadIdx.x;
    int r0 = blockIdx.x * 128;
    int lane = t & 63;
    int wv = t >> 6;          // wave 0..3
    int l15 = lane & 15;
    int lg = lane >> 4;       // 0..3

    // A-fragment source rows (clamped; OOB rows produce garbage that is never stored)
    int ra0 = r0 + wv * 32 + l15;       if (ra0 > NN - 1) ra0 = NN - 1;
    int ra1 = r0 + wv * 32 + 16 + l15;  if (ra1 > NN - 1) ra1 = NN - 1;
    const unsigned short* __restrict__ Arow0 = A + (size_t)ra0 * DIM;
    const unsigned short* __restrict__ Arow1 = A + (size_t)ra1 * DIM;

    float b1v[8], b2v[8];
#pragma unroll
    for (int nt = 0; nt < 8; ++nt) { b1v[nt] = b1[nt * 16 + l15]; b2v[nt] = b2[nt * 16 + l15]; }

    f32x4 zero4 = {0.f, 0.f, 0.f, 0.f};
    f32x4 acc[2][8];
#pragma unroll
    for (int mt = 0; mt < 2; ++mt)
#pragma unroll
        for (int nt = 0; nt < 8; ++nt) acc[mt][nt] = zero4;

    if (HOIST) {
        // grouped GEMM1 operand loads (no setprio — spill trigger, r13)
        short8 af0[4], af1[4], w1f[4][8];
#pragma unroll
        for (int ks = 0; ks < 4; ++ks) {
            int kgp = ks * 4 + lg;
            af0[ks] = *(const short8*)(Arow0 + kgp * 8);
            af1[ks] = *(const short8*)(Arow1 + kgp * 8);
#pragma unroll
            for (int nt = 0; nt < 8; ++nt)
                w1f[ks][nt] = *(const short8*)(W1d + (size_t)(kgp * 128 + nt * 16 + l15) * 8);
        }
#pragma unroll
        for (int ks = 0; ks < 4; ++ks)
#pragma unroll
            for (int nt = 0; nt < 8; ++nt) {
                acc[0][nt] = __builtin_amdgcn_mfma_f32_16x16x32_bf16(af0[ks], w1f[ks][nt], acc[0][nt], 0, 0, 0);
                acc[1][nt] = __builtin_amdgcn_mfma_f32_16x16x32_bf16(af1[ks], w1f[ks][nt], acc[1][nt], 0, 0, 0);
            }
    } else {
        // interleaved (round-11 exact)
#pragma unroll
        for (int ks = 0; ks < 4; ++ks) {
            int kgp = ks * 4 + lg;
            short8 a0 = *(const short8*)(Arow0 + kgp * 8);
            short8 a1 = *(const short8*)(Arow1 + kgp * 8);
#pragma unroll
            for (int nt = 0; nt < 8; ++nt) {
                short8 b = *(const short8*)(W1d + (size_t)(kgp * 128 + nt * 16 + l15) * 8);
                acc[0][nt] = __builtin_amdgcn_mfma_f32_16x16x32_bf16(a0, b, acc[0][nt], 0, 0, 0);
                acc[1][nt] = __builtin_amdgcn_mfma_f32_16x16x32_bf16(a1, b, acc[1][nt], 0, 0, 0);
            }
        }
    }

    // C1 -> LDS (row-major, byte-XOR (r&7)<<4), relu+bias. Wave-private rows, no sync.
#pragma unroll
    for (int mt = 0; mt < 2; ++mt)
#pragma unroll
        for (int nt = 0; nt < 8; ++nt)
#pragma unroll
            for (int rg = 0; rg < 4; ++rg) {
                int rr = wv * 32 + mt * 16 + lg * 4 + rg;
                int c = nt * 16 + l15;
                float v = fmaxf(acc[mt][nt][rg] + b1v[nt], 0.f);
                unsigned byte = (unsigned)((rr * 128 + c) * 2) ^ (unsigned)((rr & 7) << 4);
                *(unsigned short*)((char*)C1 + byte) = f2bf(v);
            }

    f32x4 acc2[2][8];
#pragma unroll
    for (int mt = 0; mt < 2; ++mt)
#pragma unroll
        for (int nt = 0; nt < 8; ++nt) acc2[mt][nt] = zero4;

    if (HOIST) {
        short8 a2f0[4], a2f1[4];
#pragma unroll
        for (int ks = 0; ks < 4; ++ks) {
            int kgp = ks * 4 + lg;
            int m0 = wv * 32 + l15, m1 = m0 + 16;
            unsigned ba0 = (unsigned)(m0 * 256 + kgp * 16) ^ (unsigned)((m0 & 7) << 4);
            unsigned ba1 = (unsigned)(m1 * 256 + kgp * 16) ^ (unsigned)((m1 & 7) << 4);
            a2f0[ks] = *(const short8*)((char*)C1 + ba0);
            a2f1[ks] = *(const short8*)((char*)C1 + ba1);
        }
        short8 w2f[4][8];
#pragma unroll
        for (int ks = 0; ks < 4; ++ks) {
            int kgp = ks * 4 + lg;
#pragma unroll
            for (int nt = 0; nt < 8; ++nt)
                w2f[ks][nt] = *(const short8*)(W2d + (size_t)(kgp * 128 + nt * 16 + l15) * 8);
        }
#pragma unroll
        for (int ks = 0; ks < 4; ++ks)
#pragma unroll
            for (int nt = 0; nt < 8; ++nt) {
                acc2[0][nt] = __builtin_amdgcn_mfma_f32_16x16x32_bf16(a2f0[ks], w2f[ks][nt], acc2[0][nt], 0, 0, 0);
                acc2[1][nt] = __builtin_amdgcn_mfma_f32_16x16x32_bf16(a2f1[ks], w2f[ks][nt], acc2[1][nt], 0, 0, 0);
            }
    } else {
#pragma unroll
        for (int ks = 0; ks < 4; ++ks) {
            int kgp = ks * 4 + lg;
            int m0 = wv * 32 + l15, m1 = m0 + 16;
            unsigned ba0 = (unsigned)(m0 * 256 + kgp * 16) ^ (unsigned)((m0 & 7) << 4);
            unsigned ba1 = (unsigned)(m1 * 256 + kgp * 16) ^ (unsigned)((m1 & 7) << 4);
            short8 a0 = *(const short8*)((char*)C1 + ba0);
            short8 a1 = *(const short8*)((char*)C1 + ba1);
#pragma unroll
            for (int nt = 0; nt < 8; ++nt) {
                short8 b = *(const short8*)(W2d + (size_t)(kgp * 128 + nt * 16 + l15) * 8);
                acc2[0][nt] = __builtin_amdgcn_mfma_f32_16x16x32_bf16(a0, b, acc2[0][nt], 0, 0, 0);
                acc2[1][nt] = __builtin_amdgcn_mfma_f32_16x16x32_bf16(a1, b, acc2[1][nt], 0, 0, 0);
            }
        }
    }

    // epilogue: store Z (scalar stores); stats via cross-lg shfl reduce + replicated atomics
#pragma unroll
    for (int nt = 0; nt < 8; ++nt) {
        float sum8 = 0.f, sq8 = 0.f;
        int c = nt * 16 + l15;
#pragma unroll
        for (int mt = 0; mt < 2; ++mt)
#pragma unroll
            for (int rg = 0; rg < 4; ++rg) {
                int rr = wv * 32 + mt * 16 + lg * 4 + rg;
                int r = r0 + rr;
                if (r < NN) {
                    float v = acc2[mt][nt][rg] + b2v[nt];
                    if (RELU2) v = fmaxf(v, 0.f);
                    Z[(size_t)r * DIM + c] = f2bf(v);
                    if (STATS) { sum8 += v; sq8 += v * v; }
                }
            }
        if (STATS) {
            sum8 += __shfl_xor(sum8, 16); sum8 += __shfl_xor(sum8, 32);
            sq8  += __shfl_xor(sq8, 16);  sq8  += __shfl_xor(sq8, 32);
            if (lg == 0) {
                float* sb = stats_base + (size_t)(blockIdx.x & (NSLOT - 1)) * 256;
                atomicAdd(&sb[c], sum8);
                atomicAdd(&sb[128 + c], sq8);
            }
        }
    }
}

// ---------------- weight conversion: fp32 [K][128] -> fragment-direct bf16 ----------------
__global__ __launch_bounds__(256) void wconv_kernel(
    const float* __restrict__ ini_w1, const float* __restrict__ ini_w2,
    const float* __restrict__ gw1, const float* __restrict__ gw2,
    unsigned short* __restrict__ Wd)
{
    int id = blockIdx.x * 256 + threadIdx.x;     // 0..16383
    int k = id >> 7, n = id & 127;
    int y = blockIdx.y;
    float v;
    if (y == 0)      v = (k < NFEAT) ? ini_w1[k * DIM + n] : 0.f;
    else if (y == 1) v = ini_w2[k * DIM + n];
    else if (y < 7)  v = gw1[(size_t)(y - 2) * DIM * DIM + k * DIM + n];
    else             v = gw2[(size_t)(y - 7) * DIM * DIM + k * DIM + n];
    int kg = k >> 3;
    Wd[(size_t)y * 16384 + (size_t)(kg * 128 + n) * 8 + (k & 7)] = f2bf(v);
}

// ---------------- x padding: fp32 [NN][78] -> bf16 [NN][128] (zero-pad) ----------------
__global__ __launch_bounds__(256) void xpad_kernel(
    const float* __restrict__ x, unsigned short* __restrict__ xp)
{
    int t = blockIdx.x * 256 + threadIdx.x;      // NN*16 exactly
    int n = t >> 4, j = t & 15;
    ushort8 o;
#pragma unroll
    for (int i = 0; i < 8; ++i) {
        int c = j * 8 + i;
        o[i] = (c < NFEAT) ? f2bf(x[(size_t)n * NFEAT + c]) : (unsigned short)0;
    }
    *(ushort8*)(xp + (size_t)n * DIM + j * 8) = o;
}

// ---------------- CSR build (once per launch) ----------------
__global__ __launch_bounds__(256) void deg_kernel(const int* __restrict__ ei, int* __restrict__ deg)
{
    int e = blockIdx.x * 256 + threadIdx.x;
    if (e >= NE) return;
    atomicAdd(&deg[ei[NE + e]], 1);
}

__global__ __launch_bounds__(256) void scanA_kernel(
    const int* __restrict__ deg, int* __restrict__ cursor, int* __restrict__ partials)
{
    __shared__ int sh[256];
    int i = blockIdx.x * 256 + threadIdx.x;
    int v = (i < NN) ? deg[i] : 0;
    sh[threadIdx.x] = v;
    __syncthreads();
    for (int off = 1; off < 256; off <<= 1) {
        int t2 = (threadIdx.x >= off) ? sh[threadIdx.x - off] : 0;
        __syncthreads();
        sh[threadIdx.x] += t2;
        __syncthreads();
    }
    int incl = sh[threadIdx.x];
    if (i < NN) cursor[i] = incl - v;
    if (threadIdx.x == 255) partials[blockIdx.x] = incl;
}

__global__ __launch_bounds__(1024) void scanB_kernel(int* __restrict__ partials, int nb)
{
    __shared__ int sh[1024];
    int i = threadIdx.x;
    int v = (i < nb) ? partials[i] : 0;
    sh[i] = v;
    __syncthreads();
    for (int off = 1; off < 1024; off <<= 1) {
        int t2 = (i >= off) ? sh[i - off] : 0;
        __syncthreads();
        sh[i] += t2;
        __syncthreads();
    }
    if (i < nb) partials[i] = sh[i] - v;
}

__global__ __launch_bounds__(256) void scanC_kernel(
    int* __restrict__ cursor, const int* __restrict__ partials)
{
    int i = blockIdx.x * 256 + threadIdx.x;
    if (i < NN) cursor[i] += partials[blockIdx.x];
}

__global__ __launch_bounds__(256) void fill_kernel(
    const int* __restrict__ ei, int* __restrict__ cursor, int* __restrict__ csr_src)
{
    int e = blockIdx.x * 256 + threadIdx.x;
    if (e >= NE) return;
    int slot = atomicAdd(&cursor[ei[NE + e]], 1);
    csr_src[slot] = ei[e];
}

// graph_ptr[g] = first node index with batch >= g (batch sorted); gptr[NGRAPHS] = NN
__global__ __launch_bounds__(256) void gptr_kernel(
    const int* __restrict__ batch, int* __restrict__ gptr)
{
    int n = blockIdx.x * 256 + threadIdx.x;
    if (n > NN) return;
    int b1 = (n < NN) ? batch[n] : NGRAPHS;
    int b0 = (n == 0) ? -1 : batch[n - 1];
    for (int g = b0 + 1; g <= b1; ++g) gptr[g] = n;
}

__global__ void ident_kernel(float* __restrict__ aff)
{
    int d = threadIdx.x;
    aff[d] = 1.f;
    aff[DIM + d] = 0.f;
}

// ---------------- affine-fused gather ----------------
// agg[n] = a ⊙ (z[n] + sum_nbr z) + (deg+1)·c ; edge loop unrolled x2 (order-preserving)
__global__ __launch_bounds__(256) void gather_kernel(
    const unsigned short* __restrict__ z, const int* __restrict__ cursor,
    const int* __restrict__ csr_src, const float* __restrict__ aff,
    unsigned short* __restrict__ agg)
{
    int t = blockIdx.x * 256 + threadIdx.x;      // NN*16 exactly
    int n = t >> 4, j = t & 15;
    int end = cursor[n];
    int beg = (n == 0) ? 0 : cursor[n - 1];
    ushort8 sv = *(const ushort8*)(z + (size_t)n * DIM + j * 8);
    float a[8];
#pragma unroll
    for (int i = 0; i < 8; ++i) a[i] = bf2f(sv[i]);
    int e = beg;
    for (; e + 1 < end; e += 2) {
        int s0 = csr_src[e];
        int s1 = csr_src[e + 1];
        ushort8 v0 = *(const ushort8*)(z + (size_t)s0 * DIM + j * 8);
        ushort8 v1 = *(const ushort8*)(z + (size_t)s1 * DIM + j * 8);
#pragma unroll
        for (int i = 0; i < 8; ++i) a[i] += bf2f(v0[i]);
#pragma unroll
        for (int i = 0; i < 8; ++i) a[i] += bf2f(v1[i]);
    }
    if (e < end) {
        int s = csr_src[e];
        ushort8 v = *(const ushort8*)(z + (size_t)s * DIM + j * 8);
#pragma unroll
        for (int i = 0; i < 8; ++i) a[i] += bf2f(v[i]);
    }
    float cnt = (float)(end - beg + 1);
    ushort8 o;
#pragma unroll
    for (int i = 0; i < 8; ++i) {
        float av = aff[j * 8 + i];
        float cv = aff[DIM + j * 8 + i];
        o[i] = f2bf(fmaf(av, a[i], cnt * cv));
    }
    *(ushort8*)(agg + (size_t)n * DIM + j * 8) = o;
}

// ---------------- per-graph pool: out[g] += lcw*(a⊙segsum(z) + cnt*c) (+ cnt*lcb) ----------------
__global__ __launch_bounds__(128) void pool_kernel(
    const unsigned short* __restrict__ z, const int* __restrict__ gptr,
    const float* __restrict__ aff, const float* __restrict__ lcw, int l,
    const float* __restrict__ lcb_p, int add_lcb, float* __restrict__ out)
{
    int g = blockIdx.x;
    int d = threadIdx.x;
    int p0 = gptr[g], p1 = gptr[g + 1];
    float S = 0.f;
    for (int n = p0; n < p1; ++n) S += bf2f(z[(size_t)n * DIM + d]);
    float w = lcw[l];
    float cnt = (float)(p1 - p0);
    float v = w * fmaf(aff[d], S, cnt * aff[DIM + d]);
    if (add_lcb) v = fmaf(cnt, *lcb_p, v);
    out[(size_t)g * DIM + d] += v;
}

// per-layer: affine[d] = gamma*rsqrt(var+eps); affine[128+d] = beta - mean*a
__global__ void finalize_kernel(
    const float* __restrict__ slots, const float* __restrict__ gamma,
    const float* __restrict__ beta, float* __restrict__ aff)
{
    int d = threadIdx.x;
    float s = 0.f, sq = 0.f;
    for (int i = 0; i < NSLOT; ++i) {
        s  += slots[i * 256 + d];
        sq += slots[i * 256 + 128 + d];
    }
    float mean = s * (1.0f / NN);
    float var = sq * (1.0f / NN) - mean * mean;
    float a = gamma[d] * rsqrtf(var + BN_EPS_C);
    aff[d] = a;
    aff[DIM + d] = beta[d] - mean * a;
}

extern "C" void kernel_launch(void* const* d_in, const int* in_sizes, int n_in,
                              void* d_out, int out_size, void* d_ws, size_t ws_size,
                              hipStream_t stream)
{
    const float* x      = (const float*)d_in[0];
    const int*   ei     = (const int*)d_in[1];
    const int*   batch  = (const int*)d_in[2];
    const float* ini_w1 = (const float*)d_in[4];
    const float* ini_b1 = (const float*)d_in[5];
    const float* ini_w2 = (const float*)d_in[6];
    const float* ini_b2 = (const float*)d_in[7];
    const float* gw1    = (const float*)d_in[8];
    const float* gb1    = (const float*)d_in[9];
    const float* gw2    = (const float*)d_in[10];
    const float* gb2    = (const float*)d_in[11];
    const float* gamma  = (const float*)d_in[12];
    const float* beta   = (const float*)d_in[13];
    const float* lcw    = (const float*)d_in[14];
    const float* lcb    = (const float*)d_in[15];
    float* out = (float*)d_out;

    size_t NHs = (size_t)NN * DIM;                       // ushort count per node buffer
    unsigned short* bufA = (unsigned short*)d_ws;
    unsigned short* bufB = bufA + NHs;                   // also holds padded x pre-ini
    unsigned short* Wd   = bufB + NHs;                   // 12 * 16384 ushorts
    float* stats  = (float*)(Wd + 12 * 16384);           // NLAYERS * NSLOT * 256
    float* affine = stats + (size_t)NLAYERS * NSLOT * 256; // (NLAYERS+1) * 256
    int* deg      = (int*)(affine + (NLAYERS + 1) * 256);
    int* cursor   = deg + NN;
    int* csr_src  = cursor + NN;
    int* partials = csr_src + NE;
    int* gptr     = partials + 1024;
    size_t need = (size_t)((char*)(gptr + NGRAPHS + 1) - (char*)d_ws);

    hipMemsetAsync(out, 0, (size_t)NGRAPHS * DIM * sizeof(float), stream);
    if (ws_size < need) return;   // diagnostic: zero output signals ws shortfall

    hipMemsetAsync(stats, 0, (size_t)NLAYERS * NSLOT * 256 * sizeof(float), stream);
    hipMemsetAsync(deg, 0, NN * sizeof(int), stream);

    int nb = (NN + 255) / 256;     // 782
    int eb = (NE + 255) / 256;

    deg_kernel<<<eb, 256, 0, stream>>>(ei, deg);
    scanA_kernel<<<nb, 256, 0, stream>>>(deg, cursor, partials);
    scanB_kernel<<<1, 1024, 0, stream>>>(partials, nb);
    scanC_kernel<<<nb, 256, 0, stream>>>(cursor, partials);
    fill_kernel<<<eb, 256, 0, stream>>>(ei, cursor, csr_src);
    gptr_kernel<<<(NN + 256) / 256 + 1, 256, 0, stream>>>(batch, gptr);
    ident_kernel<<<1, 128, 0, stream>>>(affine);

    xpad_kernel<<<NN * 16 / 256, 256, 0, stream>>>(x, bufB);
    wconv_kernel<<<dim3(64, 12), 256, 0, stream>>>(ini_w1, ini_w2, gw1, gw2, Wd);

    int gin_blocks = (NN + 127) / 128;   // 1563

    // ini_embed: bufA = relu(xp@W1+b1)@W2+b2 (no relu, no stats, interleaved body)
    gin_mlp_kernel<0, 0, 0><<<gin_blocks, 256, 0, stream>>>(
        bufB, Wd, Wd + 16384, ini_b1, ini_b2, bufA, nullptr);

    unsigned short* prev = bufA;
    for (int l = 0; l < NLAYERS; ++l) {
        unsigned short* nxt = (prev == bufA) ? bufB : bufA;
        // nxt = a_{l-1} ⊙ (z_prev + Σ z_prev[nbr]) + (deg+1)·c_{l-1}
        gather_kernel<<<NN * 16 / 256, 256, 0, stream>>>(
            prev, cursor, csr_src, affine + (size_t)l * 256, nxt);
        // nxt = relu(relu(nxt@W1+b1)@W2+b2), in-place; stats fused; grouped loads
        gin_mlp_kernel<1, 1, 1><<<gin_blocks, 256, 0, stream>>>(
            nxt, Wd + (size_t)(2 + l) * 16384, Wd + (size_t)(7 + l) * 16384,
            gb1 + l * DIM, gb2 + l * DIM, nxt, stats + (size_t)l * NSLOT * 256);
        finalize_kernel<<<1, 128, 0, stream>>>(
            stats + (size_t)l * NSLOT * 256, gamma + l * DIM, beta + l * DIM,
            affine + (size_t)(l + 1) * 256);
        // out += lcw[l]*(a_l ⊙ segsum(z_l) + cnt*c_l) (+ cnt*lcb on l==0)
        pool_kernel<<<NGRAPHS, 128, 0, stream>>>(
            nxt, gptr, affine + (size_t)(l + 1) * 256, lcw, l, lcb,
            (l == 0) ? 1 : 0, out);
        prev = nxt;
    }
}

// Round 17
// 692.232 us; speedup vs baseline: 3.2280x; 1.0620x over previous
//
#include <hip/hip_runtime.h>

#define NN 200000
#define NE 400000
#define NFEAT 78
#define DIM 128
#define NLAYERS 5
#define NGRAPHS 8192
#define BN_EPS_C 1e-5f
#define NSLOT 32

typedef __attribute__((ext_vector_type(8))) short short8;
typedef __attribute__((ext_vector_type(8))) unsigned short ushort8;
typedef __attribute__((ext_vector_type(4))) float f32x4;

__device__ inline float bf2f(unsigned short u) {
    union { unsigned int i; float f; } c; c.i = ((unsigned int)u) << 16; return c.f;
}
__device__ inline unsigned short f2bf(float f) {
    union { float f; unsigned int i; } c; c.f = f;
    unsigned int x = c.i;
    x += 0x7FFFu + ((x >> 16) & 1u);      // RNE
    return (unsigned short)(x >> 16);
}

// ---------------- fused GIN MLP: Z = maybe_relu(relu(A@W1+b1)@W2+b2) ----------------
// r14 EXACT — best measured configuration (694us total, gin 52.7us, VGPR 64, occ 30%).
// Six source-level scheduling levers tried and rejected with counter evidence:
//   r12 hoist (silently re-sunk), r13 setprio (scratch spill, 3x HBM), r15 runtime
//   half-pass loop (scratch catastrophe, 850MB/dispatch), r16 launch_bounds(256,2)
//   (occupancy 30->22%), r9/r10 LDS-bounce Z stores (2-3x HBM write amplification),
//   r8 gather fusion (latency phase under compute grid, 3.4x). This dataflow is a
//   compiler-enforced local optimum; residual gin stall is latency, not BW/compute.
// HOIST=1 (layers): grouped operand loads. HOIST=0 (ini): interleaved (r12 anomaly).
// Zero barriers (C1 rows are wave-private).
template<int RELU2, int STATS, int HOIST>
__global__ __launch_bounds__(256, 4) void gin_mlp_kernel(
    const unsigned short* __restrict__ A,
    const unsigned short* __restrict__ W1d, const unsigned short* __restrict__ W2d,
    const float* __restrict__ b1, const float* __restrict__ b2,
    unsigned short* __restrict__ Z, float* __restrict__ stats_base)
{
    __shared__ unsigned short C1[128 * 128];        // 32 KB

    int t = threadIdx.x;
    int r0 = blockIdx.x * 128;
    int lane = t & 63;
    int wv = t >> 6;          // wave 0..3
    int l15 = lane & 15;
    int lg = lane >> 4;       // 0..3

    // A-fragment source rows (clamped; OOB rows produce garbage that is never stored)
    int ra0 = r0 + wv * 32 + l15;       if (ra0 > NN - 1) ra0 = NN - 1;
    int ra1 = r0 + wv * 32 + 16 + l15;  if (ra1 > NN - 1) ra1 = NN - 1;
    const unsigned short* __restrict__ Arow0 = A + (size_t)ra0 * DIM;
    const unsigned short* __restrict__ Arow1 = A + (size_t)ra1 * DIM;

    float b1v[8], b2v[8];
#pragma unroll
    for (int nt = 0; nt < 8; ++nt) { b1v[nt] = b1[nt * 16 + l15]; b2v[nt] = b2[nt * 16 + l15]; }

    f32x4 zero4 = {0.f, 0.f, 0.f, 0.f};
    f32x4 acc[2][8];
#pragma unroll
    for (int mt = 0; mt < 2; ++mt)
#pragma unroll
        for (int nt = 0; nt < 8; ++nt) acc[mt][nt] = zero4;

    if (HOIST) {
        // grouped GEMM1 operand loads (no setprio — spill trigger, r13)
        short8 af0[4], af1[4], w1f[4][8];
#pragma unroll
        for (int ks = 0; ks < 4; ++ks) {
            int kgp = ks * 4 + lg;
            af0[ks] = *(const short8*)(Arow0 + kgp * 8);
            af1[ks] = *(const short8*)(Arow1 + kgp * 8);
#pragma unroll
            for (int nt = 0; nt < 8; ++nt)
                w1f[ks][nt] = *(const short8*)(W1d + (size_t)(kgp * 128 + nt * 16 + l15) * 8);
        }
#pragma unroll
        for (int ks = 0; ks < 4; ++ks)
#pragma unroll
            for (int nt = 0; nt < 8; ++nt) {
                acc[0][nt] = __builtin_amdgcn_mfma_f32_16x16x32_bf16(af0[ks], w1f[ks][nt], acc[0][nt], 0, 0, 0);
                acc[1][nt] = __builtin_amdgcn_mfma_f32_16x16x32_bf16(af1[ks], w1f[ks][nt], acc[1][nt], 0, 0, 0);
            }
    } else {
        // interleaved (round-11 exact)
#pragma unroll
        for (int ks = 0; ks < 4; ++ks) {
            int kgp = ks * 4 + lg;
            short8 a0 = *(const short8*)(Arow0 + kgp * 8);
            short8 a1 = *(const short8*)(Arow1 + kgp * 8);
#pragma unroll
            for (int nt = 0; nt < 8; ++nt) {
                short8 b = *(const short8*)(W1d + (size_t)(kgp * 128 + nt * 16 + l15) * 8);
                acc[0][nt] = __builtin_amdgcn_mfma_f32_16x16x32_bf16(a0, b, acc[0][nt], 0, 0, 0);
                acc[1][nt] = __builtin_amdgcn_mfma_f32_16x16x32_bf16(a1, b, acc[1][nt], 0, 0, 0);
            }
        }
    }

    // C1 -> LDS (row-major, byte-XOR (r&7)<<4), relu+bias. Wave-private rows, no sync.
#pragma unroll
    for (int mt = 0; mt < 2; ++mt)
#pragma unroll
        for (int nt = 0; nt < 8; ++nt)
#pragma unroll
            for (int rg = 0; rg < 4; ++rg) {
                int rr = wv * 32 + mt * 16 + lg * 4 + rg;
                int c = nt * 16 + l15;
                float v = fmaxf(acc[mt][nt][rg] + b1v[nt], 0.f);
                unsigned byte = (unsigned)((rr * 128 + c) * 2) ^ (unsigned)((rr & 7) << 4);
                *(unsigned short*)((char*)C1 + byte) = f2bf(v);
            }

    f32x4 acc2[2][8];
#pragma unroll
    for (int mt = 0; mt < 2; ++mt)
#pragma unroll
        for (int nt = 0; nt < 8; ++nt) acc2[mt][nt] = zero4;

    if (HOIST) {
        short8 a2f0[4], a2f1[4];
#pragma unroll
        for (int ks = 0; ks < 4; ++ks) {
            int kgp = ks * 4 + lg;
            int m0 = wv * 32 + l15, m1 = m0 + 16;
            unsigned ba0 = (unsigned)(m0 * 256 + kgp * 16) ^ (unsigned)((m0 & 7) << 4);
            unsigned ba1 = (unsigned)(m1 * 256 + kgp * 16) ^ (unsigned)((m1 & 7) << 4);
            a2f0[ks] = *(const short8*)((char*)C1 + ba0);
            a2f1[ks] = *(const short8*)((char*)C1 + ba1);
        }
        short8 w2f[4][8];
#pragma unroll
        for (int ks = 0; ks < 4; ++ks) {
            int kgp = ks * 4 + lg;
#pragma unroll
            for (int nt = 0; nt < 8; ++nt)
                w2f[ks][nt] = *(const short8*)(W2d + (size_t)(kgp * 128 + nt * 16 + l15) * 8);
        }
#pragma unroll
        for (int ks = 0; ks < 4; ++ks)
#pragma unroll
            for (int nt = 0; nt < 8; ++nt) {
                acc2[0][nt] = __builtin_amdgcn_mfma_f32_16x16x32_bf16(a2f0[ks], w2f[ks][nt], acc2[0][nt], 0, 0, 0);
                acc2[1][nt] = __builtin_amdgcn_mfma_f32_16x16x32_bf16(a2f1[ks], w2f[ks][nt], acc2[1][nt], 0, 0, 0);
            }
    } else {
#pragma unroll
        for (int ks = 0; ks < 4; ++ks) {
            int kgp = ks * 4 + lg;
            int m0 = wv * 32 + l15, m1 = m0 + 16;
            unsigned ba0 = (unsigned)(m0 * 256 + kgp * 16) ^ (unsigned)((m0 & 7) << 4);
            unsigned ba1 = (unsigned)(m1 * 256 + kgp * 16) ^ (unsigned)((m1 & 7) << 4);
            short8 a0 = *(const short8*)((char*)C1 + ba0);
            short8 a1 = *(const short8*)((char*)C1 + ba1);
#pragma unroll
            for (int nt = 0; nt < 8; ++nt) {
                short8 b = *(const short8*)(W2d + (size_t)(kgp * 128 + nt * 16 + l15) * 8);
                acc2[0][nt] = __builtin_amdgcn_mfma_f32_16x16x32_bf16(a0, b, acc2[0][nt], 0, 0, 0);
                acc2[1][nt] = __builtin_amdgcn_mfma_f32_16x16x32_bf16(a1, b, acc2[1][nt], 0, 0, 0);
            }
        }
    }

    // epilogue: store Z (scalar stores); stats via cross-lg shfl reduce + replicated atomics
#pragma unroll
    for (int nt = 0; nt < 8; ++nt) {
        float sum8 = 0.f, sq8 = 0.f;
        int c = nt * 16 + l15;
#pragma unroll
        for (int mt = 0; mt < 2; ++mt)
#pragma unroll
            for (int rg = 0; rg < 4; ++rg) {
                int rr = wv * 32 + mt * 16 + lg * 4 + rg;
                int r = r0 + rr;
                if (r < NN) {
                    float v = acc2[mt][nt][rg] + b2v[nt];
                    if (RELU2) v = fmaxf(v, 0.f);
                    Z[(size_t)r * DIM + c] = f2bf(v);
                    if (STATS) { sum8 += v; sq8 += v * v; }
                }
            }
        if (STATS) {
            sum8 += __shfl_xor(sum8, 16); sum8 += __shfl_xor(sum8, 32);
            sq8  += __shfl_xor(sq8, 16);  sq8  += __shfl_xor(sq8, 32);
            if (lg == 0) {
                float* sb = stats_base + (size_t)(blockIdx.x & (NSLOT - 1)) * 256;
                atomicAdd(&sb[c], sum8);
                atomicAdd(&sb[128 + c], sq8);
            }
        }
    }
}

// ---------------- weight conversion: fp32 [K][128] -> fragment-direct bf16 ----------------
__global__ __launch_bounds__(256) void wconv_kernel(
    const float* __restrict__ ini_w1, const float* __restrict__ ini_w2,
    const float* __restrict__ gw1, const float* __restrict__ gw2,
    unsigned short* __restrict__ Wd)
{
    int id = blockIdx.x * 256 + threadIdx.x;     // 0..16383
    int k = id >> 7, n = id & 127;
    int y = blockIdx.y;
    float v;
    if (y == 0)      v = (k < NFEAT) ? ini_w1[k * DIM + n] : 0.f;
    else if (y == 1) v = ini_w2[k * DIM + n];
    else if (y < 7)  v = gw1[(size_t)(y - 2) * DIM * DIM + k * DIM + n];
    else             v = gw2[(size_t)(y - 7) * DIM * DIM + k * DIM + n];
    int kg = k >> 3;
    Wd[(size_t)y * 16384 + (size_t)(kg * 128 + n) * 8 + (k & 7)] = f2bf(v);
}

// ---------------- x padding: fp32 [NN][78] -> bf16 [NN][128] (zero-pad) ----------------
__global__ __launch_bounds__(256) void xpad_kernel(
    const float* __restrict__ x, unsigned short* __restrict__ xp)
{
    int t = blockIdx.x * 256 + threadIdx.x;      // NN*16 exactly
    int n = t >> 4, j = t & 15;
    ushort8 o;
#pragma unroll
    for (int i = 0; i < 8; ++i) {
        int c = j * 8 + i;
        o[i] = (c < NFEAT) ? f2bf(x[(size_t)n * NFEAT + c]) : (unsigned short)0;
    }
    *(ushort8*)(xp + (size_t)n * DIM + j * 8) = o;
}

// ---------------- CSR build (once per launch) ----------------
__global__ __launch_bounds__(256) void deg_kernel(const int* __restrict__ ei, int* __restrict__ deg)
{
    int e = blockIdx.x * 256 + threadIdx.x;
    if (e >= NE) return;
    atomicAdd(&deg[ei[NE + e]], 1);
}

__global__ __launch_bounds__(256) void scanA_kernel(
    const int* __restrict__ deg, int* __restrict__ cursor, int* __restrict__ partials)
{
    __shared__ int sh[256];
    int i = blockIdx.x * 256 + threadIdx.x;
    int v = (i < NN) ? deg[i] : 0;
    sh[threadIdx.x] = v;
    __syncthreads();
    for (int off = 1; off < 256; off <<= 1) {
        int t2 = (threadIdx.x >= off) ? sh[threadIdx.x - off] : 0;
        __syncthreads();
        sh[threadIdx.x] += t2;
        __syncthreads();
    }
    int incl = sh[threadIdx.x];
    if (i < NN) cursor[i] = incl - v;
    if (threadIdx.x == 255) partials[blockIdx.x] = incl;
}

__global__ __launch_bounds__(1024) void scanB_kernel(int* __restrict__ partials, int nb)
{
    __shared__ int sh[1024];
    int i = threadIdx.x;
    int v = (i < nb) ? partials[i] : 0;
    sh[i] = v;
    __syncthreads();
    for (int off = 1; off < 1024; off <<= 1) {
        int t2 = (i >= off) ? sh[i - off] : 0;
        __syncthreads();
        sh[i] += t2;
        __syncthreads();
    }
    if (i < nb) partials[i] = sh[i] - v;
}

__global__ __launch_bounds__(256) void scanC_kernel(
    int* __restrict__ cursor, const int* __restrict__ partials)
{
    int i = blockIdx.x * 256 + threadIdx.x;
    if (i < NN) cursor[i] += partials[blockIdx.x];
}

__global__ __launch_bounds__(256) void fill_kernel(
    const int* __restrict__ ei, int* __restrict__ cursor, int* __restrict__ csr_src)
{
    int e = blockIdx.x * 256 + threadIdx.x;
    if (e >= NE) return;
    int slot = atomicAdd(&cursor[ei[NE + e]], 1);
    csr_src[slot] = ei[e];
}

// graph_ptr[g] = first node index with batch >= g (batch sorted); gptr[NGRAPHS] = NN
__global__ __launch_bounds__(256) void gptr_kernel(
    const int* __restrict__ batch, int* __restrict__ gptr)
{
    int n = blockIdx.x * 256 + threadIdx.x;
    if (n > NN) return;
    int b1 = (n < NN) ? batch[n] : NGRAPHS;
    int b0 = (n == 0) ? -1 : batch[n - 1];
    for (int g = b0 + 1; g <= b1; ++g) gptr[g] = n;
}

__global__ void ident_kernel(float* __restrict__ aff)
{
    int d = threadIdx.x;
    aff[d] = 1.f;
    aff[DIM + d] = 0.f;
}

// ---------------- affine-fused gather ----------------
// agg[n] = a ⊙ (z[n] + sum_nbr z) + (deg+1)·c ; edge loop unrolled x2 (order-preserving)
__global__ __launch_bounds__(256) void gather_kernel(
    const unsigned short* __restrict__ z, const int* __restrict__ cursor,
    const int* __restrict__ csr_src, const float* __restrict__ aff,
    unsigned short* __restrict__ agg)
{
    int t = blockIdx.x * 256 + threadIdx.x;      // NN*16 exactly
    int n = t >> 4, j = t & 15;
    int end = cursor[n];
    int beg = (n == 0) ? 0 : cursor[n - 1];
    ushort8 sv = *(const ushort8*)(z + (size_t)n * DIM + j * 8);
    float a[8];
#pragma unroll
    for (int i = 0; i < 8; ++i) a[i] = bf2f(sv[i]);
    int e = beg;
    for (; e + 1 < end; e += 2) {
        int s0 = csr_src[e];
        int s1 = csr_src[e + 1];
        ushort8 v0 = *(const ushort8*)(z + (size_t)s0 * DIM + j * 8);
        ushort8 v1 = *(const ushort8*)(z + (size_t)s1 * DIM + j * 8);
#pragma unroll
        for (int i = 0; i < 8; ++i) a[i] += bf2f(v0[i]);
#pragma unroll
        for (int i = 0; i < 8; ++i) a[i] += bf2f(v1[i]);
    }
    if (e < end) {
        int s = csr_src[e];
        ushort8 v = *(const ushort8*)(z + (size_t)s * DIM + j * 8);
#pragma unroll
        for (int i = 0; i < 8; ++i) a[i] += bf2f(v[i]);
    }
    float cnt = (float)(end - beg + 1);
    ushort8 o;
#pragma unroll
    for (int i = 0; i < 8; ++i) {
        float av = aff[j * 8 + i];
        float cv = aff[DIM + j * 8 + i];
        o[i] = f2bf(fmaf(av, a[i], cnt * cv));
    }
    *(ushort8*)(agg + (size_t)n * DIM + j * 8) = o;
}

// ---------------- per-graph pool: out[g] += lcw*(a⊙segsum(z) + cnt*c) (+ cnt*lcb) ----------------
__global__ __launch_bounds__(128) void pool_kernel(
    const unsigned short* __restrict__ z, const int* __restrict__ gptr,
    const float* __restrict__ aff, const float* __restrict__ lcw, int l,
    const float* __restrict__ lcb_p, int add_lcb, float* __restrict__ out)
{
    int g = blockIdx.x;
    int d = threadIdx.x;
    int p0 = gptr[g], p1 = gptr[g + 1];
    float S = 0.f;
    for (int n = p0; n < p1; ++n) S += bf2f(z[(size_t)n * DIM + d]);
    float w = lcw[l];
    float cnt = (float)(p1 - p0);
    float v = w * fmaf(aff[d], S, cnt * aff[DIM + d]);
    if (add_lcb) v = fmaf(cnt, *lcb_p, v);
    out[(size_t)g * DIM + d] += v;
}

// per-layer: affine[d] = gamma*rsqrt(var+eps); affine[128+d] = beta - mean*a
__global__ void finalize_kernel(
    const float* __restrict__ slots, const float* __restrict__ gamma,
    const float* __restrict__ beta, float* __restrict__ aff)
{
    int d = threadIdx.x;
    float s = 0.f, sq = 0.f;
    for (int i = 0; i < NSLOT; ++i) {
        s  += slots[i * 256 + d];
        sq += slots[i * 256 + 128 + d];
    }
    float mean = s * (1.0f / NN);
    float var = sq * (1.0f / NN) - mean * mean;
    float a = gamma[d] * rsqrtf(var + BN_EPS_C);
    aff[d] = a;
    aff[DIM + d] = beta[d] - mean * a;
}

extern "C" void kernel_launch(void* const* d_in, const int* in_sizes, int n_in,
                              void* d_out, int out_size, void* d_ws, size_t ws_size,
                              hipStream_t stream)
{
    const float* x      = (const float*)d_in[0];
    const int*   ei     = (const int*)d_in[1];
    const int*   batch  = (const int*)d_in[2];
    const float* ini_w1 = (const float*)d_in[4];
    const float* ini_b1 = (const float*)d_in[5];
    const float* ini_w2 = (const float*)d_in[6];
    const float* ini_b2 = (const float*)d_in[7];
    const float* gw1    = (const float*)d_in[8];
    const float* gb1    = (const float*)d_in[9];
    const float* gw2    = (const float*)d_in[10];
    const float* gb2    = (const float*)d_in[11];
    const float* gamma  = (const float*)d_in[12];
    const float* beta   = (const float*)d_in[13];
    const float* lcw    = (const float*)d_in[14];
    const float* lcb    = (const float*)d_in[15];
    float* out = (float*)d_out;

    size_t NHs = (size_t)NN * DIM;                       // ushort count per node buffer
    unsigned short* bufA = (unsigned short*)d_ws;
    unsigned short* bufB = bufA + NHs;                   // also holds padded x pre-ini
    unsigned short* Wd   = bufB + NHs;                   // 12 * 16384 ushorts
    float* stats  = (float*)(Wd + 12 * 16384);           // NLAYERS * NSLOT * 256
    float* affine = stats + (size_t)NLAYERS * NSLOT * 256; // (NLAYERS+1) * 256
    int* deg      = (int*)(affine + (NLAYERS + 1) * 256);
    int* cursor   = deg + NN;
    int* csr_src  = cursor + NN;
    int* partials = csr_src + NE;
    int* gptr     = partials + 1024;
    size_t need = (size_t)((char*)(gptr + NGRAPHS + 1) - (char*)d_ws);

    hipMemsetAsync(out, 0, (size_t)NGRAPHS * DIM * sizeof(float), stream);
    if (ws_size < need) return;   // diagnostic: zero output signals ws shortfall

    hipMemsetAsync(stats, 0, (size_t)NLAYERS * NSLOT * 256 * sizeof(float), stream);
    hipMemsetAsync(deg, 0, NN * sizeof(int), stream);

    int nb = (NN + 255) / 256;     // 782
    int eb = (NE + 255) / 256;

    deg_kernel<<<eb, 256, 0, stream>>>(ei, deg);
    scanA_kernel<<<nb, 256, 0, stream>>>(deg, cursor, partials);
    scanB_kernel<<<1, 1024, 0, stream>>>(partials, nb);
    scanC_kernel<<<nb, 256, 0, stream>>>(cursor, partials);
    fill_kernel<<<eb, 256, 0, stream>>>(ei, cursor, csr_src);
    gptr_kernel<<<(NN + 256) / 256 + 1, 256, 0, stream>>>(batch, gptr);
    ident_kernel<<<1, 128, 0, stream>>>(affine);

    xpad_kernel<<<NN * 16 / 256, 256, 0, stream>>>(x, bufB);
    wconv_kernel<<<dim3(64, 12), 256, 0, stream>>>(ini_w1, ini_w2, gw1, gw2, Wd);

    int gin_blocks = (NN + 127) / 128;   // 1563

    // ini_embed: bufA = relu(xp@W1+b1)@W2+b2 (no relu, no stats, interleaved body)
    gin_mlp_kernel<0, 0, 0><<<gin_blocks, 256, 0, stream>>>(
        bufB, Wd, Wd + 16384, ini_b1, ini_b2, bufA, nullptr);

    unsigned short* prev = bufA;
    for (int l = 0; l < NLAYERS; ++l) {
        unsigned short* nxt = (prev == bufA) ? bufB : bufA;
        // nxt = a_{l-1} ⊙ (z_prev + Σ z_prev[nbr]) + (deg+1)·c_{l-1}
        gather_kernel<<<NN * 16 / 256, 256, 0, stream>>>(
            prev, cursor, csr_src, affine + (size_t)l * 256, nxt);
        // nxt = relu(relu(nxt@W1+b1)@W2+b2), in-place; stats fused; grouped loads
        gin_mlp_kernel<1, 1, 1><<<gin_blocks, 256, 0, stream>>>(
            nxt, Wd + (size_t)(2 + l) * 16384, Wd + (size_t)(7 + l) * 16384,
            gb1 + l * DIM, gb2 + l * DIM, nxt, stats + (size_t)l * NSLOT * 256);
        finalize_kernel<<<1, 128, 0, stream>>>(
            stats + (size_t)l * NSLOT * 256, gamma + l * DIM, beta + l * DIM,
            affine + (size_t)(l + 1) * 256);
        // out += lcw[l]*(a_l ⊙ segsum(z_l) + cnt*c_l) (+ cnt*lcb on l==0)
        pool_kernel<<<NGRAPHS, 128, 0, stream>>>(
            nxt, gptr, affine + (size_t)(l + 1) * 256, lcw, l, lcb,
            (l == 0) ? 1 : 0, out);
        prev = nxt;
    }
}

// Round 18
// 665.403 us; speedup vs baseline: 3.3582x; 1.0403x over previous
//
#include <hip/hip_runtime.h>

#define NN 200000
#define NE 400000
#define NFEAT 78
#define DIM 128
#define NLAYERS 5
#define NGRAPHS 8192
#define BN_EPS_C 1e-5f
#define NSLOT 32

typedef __attribute__((ext_vector_type(8))) short short8;
typedef __attribute__((ext_vector_type(8))) unsigned short ushort8;
typedef __attribute__((ext_vector_type(4))) float f32x4;

__device__ inline float bf2f(unsigned short u) {
    union { unsigned int i; float f; } c; c.i = ((unsigned int)u) << 16; return c.f;
}
__device__ inline unsigned short f2bf(float f) {
    union { float f; unsigned int i; } c; c.f = f;
    unsigned int x = c.i;
    x += 0x7FFFu + ((x >> 16) & 1u);      // RNE
    return (unsigned short)(x >> 16);
}

// ---------------- fused GIN MLP: Z = maybe_relu(relu(A@W1+b1)@W2+b2) ----------------
// r14 EXACT — best measured configuration (692us total, gin 52.7us, VGPR 64, occ 30%).
// Six source-level scheduling levers tried and rejected with counter evidence:
//   r12 hoist (silently re-sunk), r13 setprio (scratch spill, 3x HBM), r15 runtime
//   half-pass loop (scratch catastrophe, 850MB/dispatch), r16 launch_bounds(256,2)
//   (occupancy 30->22%), r9/r10 LDS-bounce Z stores (2-3x HBM write amplification),
//   r8 gather fusion (latency phase under compute grid, 3.4x). This dataflow is a
//   compiler-enforced local optimum; residual gin stall is latency, not BW/compute.
// HOIST=1 (layers): grouped operand loads. HOIST=0 (ini): interleaved (r12 anomaly).
// Zero barriers (C1 rows are wave-private).
template<int RELU2, int STATS, int HOIST>
__global__ __launch_bounds__(256, 4) void gin_mlp_kernel(
    const unsigned short* __restrict__ A,
    const unsigned short* __restrict__ W1d, const unsigned short* __restrict__ W2d,
    const float* __restrict__ b1, const float* __restrict__ b2,
    unsigned short* __restrict__ Z, float* __restrict__ stats_base)
{
    __shared__ unsigned short C1[128 * 128];        // 32 KB

    int t = threadIdx.x;
    int r0 = blockIdx.x * 128;
    int lane = t & 63;
    int wv = t >> 6;          // wave 0..3
    int l15 = lane & 15;
    int lg = lane >> 4;       // 0..3

    // A-fragment source rows (clamped; OOB rows produce garbage that is never stored)
    int ra0 = r0 + wv * 32 + l15;       if (ra0 > NN - 1) ra0 = NN - 1;
    int ra1 = r0 + wv * 32 + 16 + l15;  if (ra1 > NN - 1) ra1 = NN - 1;
    const unsigned short* __restrict__ Arow0 = A + (size_t)ra0 * DIM;
    const unsigned short* __restrict__ Arow1 = A + (size_t)ra1 * DIM;

    float b1v[8], b2v[8];
#pragma unroll
    for (int nt = 0; nt < 8; ++nt) { b1v[nt] = b1[nt * 16 + l15]; b2v[nt] = b2[nt * 16 + l15]; }

    f32x4 zero4 = {0.f, 0.f, 0.f, 0.f};
    f32x4 acc[2][8];
#pragma unroll
    for (int mt = 0; mt < 2; ++mt)
#pragma unroll
        for (int nt = 0; nt < 8; ++nt) acc[mt][nt] = zero4;

    if (HOIST) {
        // grouped GEMM1 operand loads (no setprio — spill trigger, r13)
        short8 af0[4], af1[4], w1f[4][8];
#pragma unroll
        for (int ks = 0; ks < 4; ++ks) {
            int kgp = ks * 4 + lg;
            af0[ks] = *(const short8*)(Arow0 + kgp * 8);
            af1[ks] = *(const short8*)(Arow1 + kgp * 8);
#pragma unroll
            for (int nt = 0; nt < 8; ++nt)
                w1f[ks][nt] = *(const short8*)(W1d + (size_t)(kgp * 128 + nt * 16 + l15) * 8);
        }
#pragma unroll
        for (int ks = 0; ks < 4; ++ks)
#pragma unroll
            for (int nt = 0; nt < 8; ++nt) {
                acc[0][nt] = __builtin_amdgcn_mfma_f32_16x16x32_bf16(af0[ks], w1f[ks][nt], acc[0][nt], 0, 0, 0);
                acc[1][nt] = __builtin_amdgcn_mfma_f32_16x16x32_bf16(af1[ks], w1f[ks][nt], acc[1][nt], 0, 0, 0);
            }
    } else {
        // interleaved (round-11 exact)
#pragma unroll
        for (int ks = 0; ks < 4; ++ks) {
            int kgp = ks * 4 + lg;
            short8 a0 = *(const short8*)(Arow0 + kgp * 8);
            short8 a1 = *(const short8*)(Arow1 + kgp * 8);
#pragma unroll
            for (int nt = 0; nt < 8; ++nt) {
                short8 b = *(const short8*)(W1d + (size_t)(kgp * 128 + nt * 16 + l15) * 8);
                acc[0][nt] = __builtin_amdgcn_mfma_f32_16x16x32_bf16(a0, b, acc[0][nt], 0, 0, 0);
                acc[1][nt] = __builtin_amdgcn_mfma_f32_16x16x32_bf16(a1, b, acc[1][nt], 0, 0, 0);
            }
        }
    }

    // C1 -> LDS (row-major, byte-XOR (r&7)<<4), relu+bias. Wave-private rows, no sync.
#pragma unroll
    for (int mt = 0; mt < 2; ++mt)
#pragma unroll
        for (int nt = 0; nt < 8; ++nt)
#pragma unroll
            for (int rg = 0; rg < 4; ++rg) {
                int rr = wv * 32 + mt * 16 + lg * 4 + rg;
                int c = nt * 16 + l15;
                float v = fmaxf(acc[mt][nt][rg] + b1v[nt], 0.f);
                unsigned byte = (unsigned)((rr * 128 + c) * 2) ^ (unsigned)((rr & 7) << 4);
                *(unsigned short*)((char*)C1 + byte) = f2bf(v);
            }

    f32x4 acc2[2][8];
#pragma unroll
    for (int mt = 0; mt < 2; ++mt)
#pragma unroll
        for (int nt = 0; nt < 8; ++nt) acc2[mt][nt] = zero4;

    if (HOIST) {
        short8 a2f0[4], a2f1[4];
#pragma unroll
        for (int ks = 0; ks < 4; ++ks) {
            int kgp = ks * 4 + lg;
            int m0 = wv * 32 + l15, m1 = m0 + 16;
            unsigned ba0 = (unsigned)(m0 * 256 + kgp * 16) ^ (unsigned)((m0 & 7) << 4);
            unsigned ba1 = (unsigned)(m1 * 256 + kgp * 16) ^ (unsigned)((m1 & 7) << 4);
            a2f0[ks] = *(const short8*)((char*)C1 + ba0);
            a2f1[ks] = *(const short8*)((char*)C1 + ba1);
        }
        short8 w2f[4][8];
#pragma unroll
        for (int ks = 0; ks < 4; ++ks) {
            int kgp = ks * 4 + lg;
#pragma unroll
            for (int nt = 0; nt < 8; ++nt)
                w2f[ks][nt] = *(const short8*)(W2d + (size_t)(kgp * 128 + nt * 16 + l15) * 8);
        }
#pragma unroll
        for (int ks = 0; ks < 4; ++ks)
#pragma unroll
            for (int nt = 0; nt < 8; ++nt) {
                acc2[0][nt] = __builtin_amdgcn_mfma_f32_16x16x32_bf16(a2f0[ks], w2f[ks][nt], acc2[0][nt], 0, 0, 0);
                acc2[1][nt] = __builtin_amdgcn_mfma_f32_16x16x32_bf16(a2f1[ks], w2f[ks][nt], acc2[1][nt], 0, 0, 0);
            }
    } else {
#pragma unroll
        for (int ks = 0; ks < 4; ++ks) {
            int kgp = ks * 4 + lg;
            int m0 = wv * 32 + l15, m1 = m0 + 16;
            unsigned ba0 = (unsigned)(m0 * 256 + kgp * 16) ^ (unsigned)((m0 & 7) << 4);
            unsigned ba1 = (unsigned)(m1 * 256 + kgp * 16) ^ (unsigned)((m1 & 7) << 4);
            short8 a0 = *(const short8*)((char*)C1 + ba0);
            short8 a1 = *(const short8*)((char*)C1 + ba1);
#pragma unroll
            for (int nt = 0; nt < 8; ++nt) {
                short8 b = *(const short8*)(W2d + (size_t)(kgp * 128 + nt * 16 + l15) * 8);
                acc2[0][nt] = __builtin_amdgcn_mfma_f32_16x16x32_bf16(a0, b, acc2[0][nt], 0, 0, 0);
                acc2[1][nt] = __builtin_amdgcn_mfma_f32_16x16x32_bf16(a1, b, acc2[1][nt], 0, 0, 0);
            }
        }
    }

    // epilogue: store Z (scalar stores); stats via cross-lg shfl reduce + replicated atomics
#pragma unroll
    for (int nt = 0; nt < 8; ++nt) {
        float sum8 = 0.f, sq8 = 0.f;
        int c = nt * 16 + l15;
#pragma unroll
        for (int mt = 0; mt < 2; ++mt)
#pragma unroll
            for (int rg = 0; rg < 4; ++rg) {
                int rr = wv * 32 + mt * 16 + lg * 4 + rg;
                int r = r0 + rr;
                if (r < NN) {
                    float v = acc2[mt][nt][rg] + b2v[nt];
                    if (RELU2) v = fmaxf(v, 0.f);
                    Z[(size_t)r * DIM + c] = f2bf(v);
                    if (STATS) { sum8 += v; sq8 += v * v; }
                }
            }
        if (STATS) {
            sum8 += __shfl_xor(sum8, 16); sum8 += __shfl_xor(sum8, 32);
            sq8  += __shfl_xor(sq8, 16);  sq8  += __shfl_xor(sq8, 32);
            if (lg == 0) {
                float* sb = stats_base + (size_t)(blockIdx.x & (NSLOT - 1)) * 256;
                atomicAdd(&sb[c], sum8);
                atomicAdd(&sb[128 + c], sq8);
            }
        }
    }
}

// ---------------- weight conversion: fp32 [K][128] -> fragment-direct bf16 ----------------
__global__ __launch_bounds__(256) void wconv_kernel(
    const float* __restrict__ ini_w1, const float* __restrict__ ini_w2,
    const float* __restrict__ gw1, const float* __restrict__ gw2,
    unsigned short* __restrict__ Wd)
{
    int id = blockIdx.x * 256 + threadIdx.x;     // 0..16383
    int k = id >> 7, n = id & 127;
    int y = blockIdx.y;
    float v;
    if (y == 0)      v = (k < NFEAT) ? ini_w1[k * DIM + n] : 0.f;
    else if (y == 1) v = ini_w2[k * DIM + n];
    else if (y < 7)  v = gw1[(size_t)(y - 2) * DIM * DIM + k * DIM + n];
    else             v = gw2[(size_t)(y - 7) * DIM * DIM + k * DIM + n];
    int kg = k >> 3;
    Wd[(size_t)y * 16384 + (size_t)(kg * 128 + n) * 8 + (k & 7)] = f2bf(v);
}

// ---------------- x padding: fp32 [NN][78] -> bf16 [NN][128] (zero-pad) ----------------
__global__ __launch_bounds__(256) void xpad_kernel(
    const float* __restrict__ x, unsigned short* __restrict__ xp)
{
    int t = blockIdx.x * 256 + threadIdx.x;      // NN*16 exactly
    int n = t >> 4, j = t & 15;
    ushort8 o;
#pragma unroll
    for (int i = 0; i < 8; ++i) {
        int c = j * 8 + i;
        o[i] = (c < NFEAT) ? f2bf(x[(size_t)n * NFEAT + c]) : (unsigned short)0;
    }
    *(ushort8*)(xp + (size_t)n * DIM + j * 8) = o;
}

// ---------------- CSR build (once per launch) ----------------
__global__ __launch_bounds__(256) void deg_kernel(const int* __restrict__ ei, int* __restrict__ deg)
{
    int e = blockIdx.x * 256 + threadIdx.x;
    if (e >= NE) return;
    atomicAdd(&deg[ei[NE + e]], 1);
}

__global__ __launch_bounds__(256) void scanA_kernel(
    const int* __restrict__ deg, int* __restrict__ cursor, int* __restrict__ partials)
{
    __shared__ int sh[256];
    int i = blockIdx.x * 256 + threadIdx.x;
    int v = (i < NN) ? deg[i] : 0;
    sh[threadIdx.x] = v;
    __syncthreads();
    for (int off = 1; off < 256; off <<= 1) {
        int t2 = (threadIdx.x >= off) ? sh[threadIdx.x - off] : 0;
        __syncthreads();
        sh[threadIdx.x] += t2;
        __syncthreads();
    }
    int incl = sh[threadIdx.x];
    if (i < NN) cursor[i] = incl - v;
    if (threadIdx.x == 255) partials[blockIdx.x] = incl;
}

__global__ __launch_bounds__(1024) void scanB_kernel(int* __restrict__ partials, int nb)
{
    __shared__ int sh[1024];
    int i = threadIdx.x;
    int v = (i < nb) ? partials[i] : 0;
    sh[i] = v;
    __syncthreads();
    for (int off = 1; off < 1024; off <<= 1) {
        int t2 = (i >= off) ? sh[i - off] : 0;
        __syncthreads();
        sh[i] += t2;
        __syncthreads();
    }
    if (i < nb) partials[i] = sh[i] - v;
}

__global__ __launch_bounds__(256) void scanC_kernel(
    int* __restrict__ cursor, const int* __restrict__ partials)
{
    int i = blockIdx.x * 256 + threadIdx.x;
    if (i < NN) cursor[i] += partials[blockIdx.x];
}

__global__ __launch_bounds__(256) void fill_kernel(
    const int* __restrict__ ei, int* __restrict__ cursor, int* __restrict__ csr_src)
{
    int e = blockIdx.x * 256 + threadIdx.x;
    if (e >= NE) return;
    int slot = atomicAdd(&cursor[ei[NE + e]], 1);
    csr_src[slot] = ei[e];
}

// graph_ptr[g] = first node index with batch >= g (batch sorted); gptr[NGRAPHS] = NN
__global__ __launch_bounds__(256) void gptr_kernel(
    const int* __restrict__ batch, int* __restrict__ gptr)
{
    int n = blockIdx.x * 256 + threadIdx.x;
    if (n > NN) return;
    int b1 = (n < NN) ? batch[n] : NGRAPHS;
    int b0 = (n == 0) ? -1 : batch[n - 1];
    for (int g = b0 + 1; g <= b1; ++g) gptr[g] = n;
}

__global__ void ident_kernel(float* __restrict__ aff)
{
    int d = threadIdx.x;
    aff[d] = 1.f;
    aff[DIM + d] = 0.f;
}

// ---------------- affine-fused gather ----------------
// agg[n] = a ⊙ (z[n] + sum_nbr z) + (deg+1)·c
// 8 threads/node (16 features each, 2x ushort8 per row): halves replicated
// cursor/csr_src scalar loads vs 16/node, doubles independent loads in flight.
// Per-feature accumulation order identical to previous version (bit-exact).
__global__ __launch_bounds__(256) void gather_kernel(
    const unsigned short* __restrict__ z, const int* __restrict__ cursor,
    const int* __restrict__ csr_src, const float* __restrict__ aff,
    unsigned short* __restrict__ agg)
{
    int t = blockIdx.x * 256 + threadIdx.x;      // NN*8 exactly
    int n = t >> 3, j = t & 7;                   // j selects 16-feature chunk
    int end = cursor[n];
    int beg = (n == 0) ? 0 : cursor[n - 1];
    const unsigned short* __restrict__ zp = z + (size_t)n * DIM + j * 16;
    ushort8 sv0 = *(const ushort8*)(zp);
    ushort8 sv1 = *(const ushort8*)(zp + 8);
    float a[16];
#pragma unroll
    for (int i = 0; i < 8; ++i) { a[i] = bf2f(sv0[i]); a[8 + i] = bf2f(sv1[i]); }
    int e = beg;
    for (; e + 1 < end; e += 2) {
        int s0 = csr_src[e];
        int s1 = csr_src[e + 1];
        const unsigned short* p0 = z + (size_t)s0 * DIM + j * 16;
        const unsigned short* p1 = z + (size_t)s1 * DIM + j * 16;
        ushort8 u0 = *(const ushort8*)(p0);
        ushort8 u1 = *(const ushort8*)(p0 + 8);
        ushort8 w0 = *(const ushort8*)(p1);
        ushort8 w1 = *(const ushort8*)(p1 + 8);
#pragma unroll
        for (int i = 0; i < 8; ++i) { a[i] += bf2f(u0[i]); a[8 + i] += bf2f(u1[i]); }
#pragma unroll
        for (int i = 0; i < 8; ++i) { a[i] += bf2f(w0[i]); a[8 + i] += bf2f(w1[i]); }
    }
    if (e < end) {
        int s = csr_src[e];
        const unsigned short* p = z + (size_t)s * DIM + j * 16;
        ushort8 u0 = *(const ushort8*)(p);
        ushort8 u1 = *(const ushort8*)(p + 8);
#pragma unroll
        for (int i = 0; i < 8; ++i) { a[i] += bf2f(u0[i]); a[8 + i] += bf2f(u1[i]); }
    }
    float cnt = (float)(end - beg + 1);
    ushort8 o0, o1;
#pragma unroll
    for (int i = 0; i < 8; ++i) {
        float av0 = aff[j * 16 + i];
        float cv0 = aff[DIM + j * 16 + i];
        o0[i] = f2bf(fmaf(av0, a[i], cnt * cv0));
        float av1 = aff[j * 16 + 8 + i];
        float cv1 = aff[DIM + j * 16 + 8 + i];
        o1[i] = f2bf(fmaf(av1, a[8 + i], cnt * cv1));
    }
    unsigned short* op = agg + (size_t)n * DIM + j * 16;
    *(ushort8*)(op) = o0;
    *(ushort8*)(op + 8) = o1;
}

// ---------------- per-graph pool: out[g] += lcw*(a⊙segsum(z) + cnt*c) (+ cnt*lcb) ----------------
// 64 threads/graph, 2 features/thread via one packed-bf16 4B load per row
// (wave reads a full 256B row coalesced). Node order unchanged (bit-exact).
__global__ __launch_bounds__(64) void pool_kernel(
    const unsigned short* __restrict__ z, const int* __restrict__ gptr,
    const float* __restrict__ aff, const float* __restrict__ lcw, int l,
    const float* __restrict__ lcb_p, int add_lcb, float* __restrict__ out)
{
    int g = blockIdx.x;
    int j = threadIdx.x;                 // 0..63, features 2j, 2j+1
    int p0 = gptr[g], p1 = gptr[g + 1];
    float S0 = 0.f, S1 = 0.f;
    for (int n = p0; n < p1; ++n) {
        unsigned u = *(const unsigned*)(z + (size_t)n * DIM + 2 * j);
        S0 += bf2f((unsigned short)(u & 0xFFFFu));
        S1 += bf2f((unsigned short)(u >> 16));
    }
    float w = lcw[l];
    float cnt = (float)(p1 - p0);
    float v0 = w * fmaf(aff[2 * j], S0, cnt * aff[DIM + 2 * j]);
    float v1 = w * fmaf(aff[2 * j + 1], S1, cnt * aff[DIM + 2 * j + 1]);
    if (add_lcb) {
        float lb = *lcb_p;
        v0 = fmaf(cnt, lb, v0);
        v1 = fmaf(cnt, lb, v1);
    }
    float* op = out + (size_t)g * DIM + 2 * j;
    op[0] += v0;
    op[1] += v1;
}

// per-layer: affine[d] = gamma*rsqrt(var+eps); affine[128+d] = beta - mean*a
__global__ void finalize_kernel(
    const float* __restrict__ slots, const float* __restrict__ gamma,
    const float* __restrict__ beta, float* __restrict__ aff)
{
    int d = threadIdx.x;
    float s = 0.f, sq = 0.f;
    for (int i = 0; i < NSLOT; ++i) {
        s  += slots[i * 256 + d];
        sq += slots[i * 256 + 128 + d];
    }
    float mean = s * (1.0f / NN);
    float var = sq * (1.0f / NN) - mean * mean;
    float a = gamma[d] * rsqrtf(var + BN_EPS_C);
    aff[d] = a;
    aff[DIM + d] = beta[d] - mean * a;
}

extern "C" void kernel_launch(void* const* d_in, const int* in_sizes, int n_in,
                              void* d_out, int out_size, void* d_ws, size_t ws_size,
                              hipStream_t stream)
{
    const float* x      = (const float*)d_in[0];
    const int*   ei     = (const int*)d_in[1];
    const int*   batch  = (const int*)d_in[2];
    const float* ini_w1 = (const float*)d_in[4];
    const float* ini_b1 = (const float*)d_in[5];
    const float* ini_w2 = (const float*)d_in[6];
    const float* ini_b2 = (const float*)d_in[7];
    const float* gw1    = (const float*)d_in[8];
    const float* gb1    = (const float*)d_in[9];
    const float* gw2    = (const float*)d_in[10];
    const float* gb2    = (const float*)d_in[11];
    const float* gamma  = (const float*)d_in[12];
    const float* beta   = (const float*)d_in[13];
    const float* lcw    = (const float*)d_in[14];
    const float* lcb    = (const float*)d_in[15];
    float* out = (float*)d_out;

    size_t NHs = (size_t)NN * DIM;                       // ushort count per node buffer
    unsigned short* bufA = (unsigned short*)d_ws;
    unsigned short* bufB = bufA + NHs;                   // also holds padded x pre-ini
    unsigned short* Wd   = bufB + NHs;                   // 12 * 16384 ushorts
    float* stats  = (float*)(Wd + 12 * 16384);           // NLAYERS * NSLOT * 256
    float* affine = stats + (size_t)NLAYERS * NSLOT * 256; // (NLAYERS+1) * 256
    int* deg      = (int*)(affine + (NLAYERS + 1) * 256);
    int* cursor   = deg + NN;
    int* csr_src  = cursor + NN;
    int* partials = csr_src + NE;
    int* gptr     = partials + 1024;
    size_t need = (size_t)((char*)(gptr + NGRAPHS + 1) - (char*)d_ws);

    hipMemsetAsync(out, 0, (size_t)NGRAPHS * DIM * sizeof(float), stream);
    if (ws_size < need) return;   // diagnostic: zero output signals ws shortfall

    hipMemsetAsync(stats, 0, (size_t)NLAYERS * NSLOT * 256 * sizeof(float), stream);
    hipMemsetAsync(deg, 0, NN * sizeof(int), stream);

    int nb = (NN + 255) / 256;     // 782
    int eb = (NE + 255) / 256;

    deg_kernel<<<eb, 256, 0, stream>>>(ei, deg);
    scanA_kernel<<<nb, 256, 0, stream>>>(deg, cursor, partials);
    scanB_kernel<<<1, 1024, 0, stream>>>(partials, nb);
    scanC_kernel<<<nb, 256, 0, stream>>>(cursor, partials);
    fill_kernel<<<eb, 256, 0, stream>>>(ei, cursor, csr_src);
    gptr_kernel<<<(NN + 256) / 256 + 1, 256, 0, stream>>>(batch, gptr);
    ident_kernel<<<1, 128, 0, stream>>>(affine);

    xpad_kernel<<<NN * 16 / 256, 256, 0, stream>>>(x, bufB);
    wconv_kernel<<<dim3(64, 12), 256, 0, stream>>>(ini_w1, ini_w2, gw1, gw2, Wd);

    int gin_blocks = (NN + 127) / 128;   // 1563

    // ini_embed: bufA = relu(xp@W1+b1)@W2+b2 (no relu, no stats, interleaved body)
    gin_mlp_kernel<0, 0, 0><<<gin_blocks, 256, 0, stream>>>(
        bufB, Wd, Wd + 16384, ini_b1, ini_b2, bufA, nullptr);

    unsigned short* prev = bufA;
    for (int l = 0; l < NLAYERS; ++l) {
        unsigned short* nxt = (prev == bufA) ? bufB : bufA;
        // nxt = a_{l-1} ⊙ (z_prev + Σ z_prev[nbr]) + (deg+1)·c_{l-1}
        gather_kernel<<<NN * 8 / 256, 256, 0, stream>>>(
            prev, cursor, csr_src, affine + (size_t)l * 256, nxt);
        // nxt = relu(relu(nxt@W1+b1)@W2+b2), in-place; stats fused; grouped loads
        gin_mlp_kernel<1, 1, 1><<<gin_blocks, 256, 0, stream>>>(
            nxt, Wd + (size_t)(2 + l) * 16384, Wd + (size_t)(7 + l) * 16384,
            gb1 + l * DIM, gb2 + l * DIM, nxt, stats + (size_t)l * NSLOT * 256);
        finalize_kernel<<<1, 128, 0, stream>>>(
            stats + (size_t)l * NSLOT * 256, gamma + l * DIM, beta + l * DIM,
            affine + (size_t)(l + 1) * 256);
        // out += lcw[l]*(a_l ⊙ segsum(z_l) + cnt*c_l) (+ cnt*lcb on l==0)
        pool_kernel<<<NGRAPHS, 64, 0, stream>>>(
            nxt, gptr, affine + (size_t)(l + 1) * 256, lcw, l, lcb,
            (l == 0) ? 1 : 0, out);
        prev = nxt;
    }
}